// Round 3
// baseline (170.175 us; speedup 1.0000x reference)
//
#include <hip/hip_runtime.h>

#define BB 32
#define NN 256
#define DIN 512
#define DD 256
#define HH 512
#define MM 8192      // BB*NN
#define NDG 65536    // NN*DD
#define KSTR 16

typedef __attribute__((ext_vector_type(8))) __bf16 bf16x8;
typedef __attribute__((ext_vector_type(4))) float f32x4;

__device__ __forceinline__ unsigned short f2bf(float x) {
  unsigned u = __float_as_uint(x);
  u += 0x7FFFu + ((u >> 16) & 1u);   // round-to-nearest-even
  return (unsigned short)(u >> 16);
}

// ---------------- K1: xie = xi @ W_img + b_img  (8192x512 @ 512x256) ----------
// Streaming form: block = 32 rows, LDS holds A tile [32][512] (natural layout),
// inner loop reads A via wave-uniform broadcast float4 along k; W_img rows are
// streamed from global (L2-resident, 512 KB). 2 k-teams, fp32 exact.
// Epilogue also emits bf16 xie into A_bf cols 0..255 (fused k_cvtx).
__global__ __launch_bounds__(256, 4) void k_enc(const float* __restrict__ A,
                                                const float* __restrict__ W,
                                                const float* __restrict__ bias,
                                                float* __restrict__ C,
                                                unsigned short* __restrict__ A_bf) {
  __shared__ float Asm[32][516];
  const int tid = threadIdx.x;
  const int mb0 = blockIdx.x * 32;
  const int cq = tid & 63;            // 64 col-quads -> 256 cols
  const int team = (tid >> 6) & 1;    // k halves of 256
  const int mh = tid >> 7;            // m halves of 16
#pragma unroll
  for (int i = 0; i < 16; ++i) {
    int idx = tid + i * 256;          // 0..4095 = 32 rows x 128 quads
    int m = idx >> 7;
    int kq = idx & 127;
    float4 v = *reinterpret_cast<const float4*>(&A[(size_t)(mb0 + m) * DIN + kq * 4]);
    *reinterpret_cast<float4*>(&Asm[m][kq * 4]) = v;
  }
  __syncthreads();
  float4 acc[16];
#pragma unroll
  for (int m = 0; m < 16; ++m) acc[m] = make_float4(0.f, 0.f, 0.f, 0.f);
  const int kt0 = team * 256;
  const float* wp = &W[(size_t)kt0 * DD + cq * 4];
  float4 wc[4], wn[4];
#pragma unroll
  for (int j = 0; j < 4; ++j)
    wc[j] = *reinterpret_cast<const float4*>(&wp[(size_t)j * DD]);
  for (int it = 0; it < 64; ++it) {
    if (it < 63) {
#pragma unroll
      for (int j = 0; j < 4; ++j)
        wn[j] = *reinterpret_cast<const float4*>(&wp[(size_t)((it + 1) * 4 + j) * DD]);
    }
    const int kk = kt0 + it * 4;
#pragma unroll
    for (int m = 0; m < 16; ++m) {
      float4 a = *reinterpret_cast<const float4*>(&Asm[mh * 16 + m][kk]);
      acc[m].x += a.x * wc[0].x; acc[m].y += a.x * wc[0].y;
      acc[m].z += a.x * wc[0].z; acc[m].w += a.x * wc[0].w;
      acc[m].x += a.y * wc[1].x; acc[m].y += a.y * wc[1].y;
      acc[m].z += a.y * wc[1].z; acc[m].w += a.y * wc[1].w;
      acc[m].x += a.z * wc[2].x; acc[m].y += a.z * wc[2].y;
      acc[m].z += a.z * wc[2].z; acc[m].w += a.z * wc[2].w;
      acc[m].x += a.w * wc[3].x; acc[m].y += a.w * wc[3].y;
      acc[m].z += a.w * wc[3].z; acc[m].w += a.w * wc[3].w;
    }
#pragma unroll
    for (int j = 0; j < 4; ++j) wc[j] = wn[j];
  }
  // cross-team reduce through LDS (A tile dead)
  float* red = &Asm[0][0];
  __syncthreads();
  if (team == 1) {
#pragma unroll
    for (int m = 0; m < 16; ++m)
      *reinterpret_cast<float4*>(&red[(mh * 16 + m) * 256 + cq * 4]) = acc[m];
  }
  __syncthreads();
  if (team == 0) {
    float4 bv = *reinterpret_cast<const float4*>(&bias[cq * 4]);
#pragma unroll
    for (int m = 0; m < 16; ++m) {
      float4 o = *reinterpret_cast<float4*>(&red[(mh * 16 + m) * 256 + cq * 4]);
      float4 s;
      s.x = acc[m].x + o.x + bv.x;
      s.y = acc[m].y + o.y + bv.y;
      s.z = acc[m].z + o.z + bv.z;
      s.w = acc[m].w + o.w + bv.w;
      const int row = mb0 + mh * 16 + m;
      *reinterpret_cast<float4*>(&C[(size_t)row * DD + cq * 4]) = s;
      ushort4 ob;
      ob.x = f2bf(s.x); ob.y = f2bf(s.y); ob.z = f2bf(s.z); ob.w = f2bf(s.w);
      *reinterpret_cast<ushort4*>(&A_bf[(size_t)row * 512 + cq * 4]) = ob;
    }
  }
}

// ---------------- K1b: row norms ----------------------------------------------
__global__ __launch_bounds__(256) void k_norm(const float* __restrict__ X,
                                              float* __restrict__ x2) {
  const int tid = threadIdx.x;
  const int row = blockIdx.x * 4 + (tid >> 6);
  const int lane = tid & 63;
  float4 v = *reinterpret_cast<const float4*>(&X[row * DD + lane * 4]);
  float s = v.x * v.x + v.y * v.y + v.z * v.z + v.w * v.w;
#pragma unroll
  for (int off = 1; off < 64; off <<= 1) s += __shfl_xor(s, off);
  if (lane == 0) x2[row] = s;
}

// ---------------- K2a: pairwise d2 --------------------------------------------
__global__ __launch_bounds__(256) void k_dist(const float* __restrict__ X,
                                              const float* __restrict__ x2,
                                              float* __restrict__ d2) {
  __shared__ float As[16][68];
  __shared__ float Bs[16][68];
  const int tid = threadIdx.x;
  const int b = blockIdx.z;
  const int m0 = blockIdx.x * 64, n0 = blockIdx.y * 64;
  const float* Xb = X + b * NN * DD;
  const int tx = tid & 15, ty = tid >> 4;
  const int lrow = tid >> 2, lfc = (tid & 3) * 4;
  float acc[4][4] = {};
  for (int k0 = 0; k0 < DD; k0 += 16) {
    float4 va = *reinterpret_cast<const float4*>(&Xb[(n0 + lrow) * DD + k0 + lfc]);
    As[lfc + 0][lrow] = va.x; As[lfc + 1][lrow] = va.y;
    As[lfc + 2][lrow] = va.z; As[lfc + 3][lrow] = va.w;
    float4 vb = *reinterpret_cast<const float4*>(&Xb[(m0 + lrow) * DD + k0 + lfc]);
    Bs[lfc + 0][lrow] = vb.x; Bs[lfc + 1][lrow] = vb.y;
    Bs[lfc + 2][lrow] = vb.z; Bs[lfc + 3][lrow] = vb.w;
    __syncthreads();
#pragma unroll
    for (int kk = 0; kk < 16; ++kk) {
      float a[4], bv[4];
      *reinterpret_cast<float4*>(a) = *reinterpret_cast<float4*>(&As[kk][ty * 4]);
      *reinterpret_cast<float4*>(bv) = *reinterpret_cast<float4*>(&Bs[kk][tx * 4]);
#pragma unroll
      for (int i = 0; i < 4; ++i)
#pragma unroll
        for (int j = 0; j < 4; ++j) acc[i][j] += a[i] * bv[j];
    }
    __syncthreads();
  }
#pragma unroll
  for (int i = 0; i < 4; ++i) {
    const int n = n0 + ty * 4 + i;
    const float xn = x2[b * NN + n];
    float4 v;
    float* vv = reinterpret_cast<float*>(&v);
#pragma unroll
    for (int j = 0; j < 4; ++j) {
      const int mc = m0 + tx * 4 + j;
      float dv = xn + x2[b * NN + mc] - 2.0f * acc[i][j];
      if (n == mc) dv = 1e30f;
      vv[j] = dv;
    }
    *reinterpret_cast<float4*>(&d2[(b * NN + n) * NN + m0 + tx * 4]) = v;
  }
}

// ---------------- K2b: per-row top-k ------------------------------------------
__global__ __launch_bounds__(256) void k_topk(const float* __restrict__ d2,
                                              const int* __restrict__ kp,
                                              int* __restrict__ nbr) {
  const int tid = threadIdx.x;
  const int i = blockIdx.x * 4 + (tid >> 6);
  const int lane = tid & 63;
  const int kcnt = kp[0];
  const float* row = d2 + (size_t)i * NN;
  float v0 = row[lane];
  float v1 = row[lane + 64];
  float v2 = row[lane + 128];
  float v3 = row[lane + 192];
  for (int it = 0; it < kcnt; ++it) {
    float v = v0; int idx = lane;
    if (v1 < v) { v = v1; idx = lane + 64; }
    if (v2 < v) { v = v2; idx = lane + 128; }
    if (v3 < v) { v = v3; idx = lane + 192; }
#pragma unroll
    for (int off = 1; off < 64; off <<= 1) {
      float ov = __shfl_xor(v, off);
      int oi = __shfl_xor(idx, off);
      if (ov < v || (ov == v && oi < idx)) { v = ov; idx = oi; }
    }
    if (lane == 0) nbr[i * KSTR + it] = idx;
    const int slot = idx >> 6;
    if (lane == (idx & 63)) {
      if (slot == 0) v0 = 3e38f;
      else if (slot == 1) v1 = 3e38f;
      else if (slot == 2) v2 = 3e38f;
      else v3 = 3e38f;
    }
  }
}

// ---------------- K3: agg (bf16, written into packed A_bf cols 256..511) ------
__global__ __launch_bounds__(256) void k_agg(const float* __restrict__ X,
                                             const int* __restrict__ nbr,
                                             const int* __restrict__ kp,
                                             unsigned short* __restrict__ A_bf) {
  const int i = blockIdx.x;
  const int b = i >> 8;
  const int t = threadIdx.x;
  const int kcnt = kp[0];
  float acc = 0.0f;
  for (int j = 0; j < kcnt; ++j) {
    const int nb = nbr[i * KSTR + j];
    acc += X[(b * NN + nb) * DD + t];
  }
  A_bf[(size_t)i * 512 + 256 + t] = f2bf(acc / (float)kcnt);
}

// ---------------- cvt: [Ws;Wn] -> bf16 transposed B_bfT[n][k] -----------------
__global__ __launch_bounds__(256) void k_cvtw(const float* __restrict__ Ws,
                                              const float* __restrict__ Wn,
                                              unsigned short* __restrict__ B_bfT) {
  const int id = blockIdx.x * 256 + threadIdx.x;    // 0 .. 131071
  const int k = id >> 8;
  const int n = id & 255;
  float v = (k < 256) ? Ws[k * 256 + n] : Wn[(k - 256) * 256 + n];
  B_bfT[(size_t)n * 512 + k] = f2bf(v);
}

// ---------------- K4: gep = relu(A_bf @ B_bfT^T + b) via bf16 MFMA ------------
__global__ __launch_bounds__(256) void k_gnn(const unsigned short* __restrict__ A_bf,
                                             const unsigned short* __restrict__ B_bfT,
                                             const float* __restrict__ bias,
                                             float* __restrict__ C) {
  __shared__ unsigned short As[64 * 72];
  __shared__ unsigned short Bs[64 * 72];
  const int tid = threadIdx.x;
  const int m0 = blockIdx.x * 64, n0 = blockIdx.y * 64;
  const int l = tid & 63, w = tid >> 6;
  const int mw = (w & 1) * 32, nw = (w >> 1) * 32;
  const int lr = tid >> 3, lq = tid & 7;
  f32x4 acc[2][2] = {};
  for (int kt = 0; kt < 8; ++kt) {
    const int kb = kt * 64;
#pragma unroll
    for (int s = 0; s < 2; ++s) {
      const int r = lr + s * 32;
      uint4 va = *reinterpret_cast<const uint4*>(&A_bf[(size_t)(m0 + r) * 512 + kb + lq * 8]);
      *reinterpret_cast<uint4*>(&As[r * 72 + lq * 8]) = va;
      uint4 vb = *reinterpret_cast<const uint4*>(&B_bfT[(size_t)(n0 + r) * 512 + kb + lq * 8]);
      *reinterpret_cast<uint4*>(&Bs[r * 72 + lq * 8]) = vb;
    }
    __syncthreads();
#pragma unroll
    for (int ks = 0; ks < 2; ++ks) {
      bf16x8 af[2], bf[2];
#pragma unroll
      for (int mi = 0; mi < 2; ++mi)
        af[mi] = *reinterpret_cast<const bf16x8*>(
            &As[(mw + mi * 16 + (l & 15)) * 72 + ks * 32 + (l >> 4) * 8]);
#pragma unroll
      for (int ni = 0; ni < 2; ++ni)
        bf[ni] = *reinterpret_cast<const bf16x8*>(
            &Bs[(nw + ni * 16 + (l & 15)) * 72 + ks * 32 + (l >> 4) * 8]);
#pragma unroll
      for (int mi = 0; mi < 2; ++mi)
#pragma unroll
        for (int ni = 0; ni < 2; ++ni)
          acc[mi][ni] = __builtin_amdgcn_mfma_f32_16x16x32_bf16(af[mi], bf[ni],
                                                                acc[mi][ni], 0, 0, 0);
    }
    __syncthreads();
  }
#pragma unroll
  for (int mi = 0; mi < 2; ++mi) {
    const int row_base = m0 + mw + mi * 16 + (l >> 4) * 4;
#pragma unroll
    for (int ni = 0; ni < 2; ++ni) {
      const int col = n0 + nw + ni * 16 + (l & 15);
      const float bv = bias[col];
#pragma unroll
      for (int r = 0; r < 4; ++r) {
        float v = acc[mi][ni][r] + bv;
        C[(size_t)(row_base + r) * 256 + col] = v > 0.0f ? v : 0.0f;
      }
    }
  }
}

// ---------------- K5: h partials = gep_flat[32,65536] @ W1, k-chunked ---------
// 256 blocks x 1024 threads. Block b owns k in [b*256, b*256+256).
// A tile [32][256] in LDS natural layout; inner loop reads A with wave-uniform
// broadcast float4 along k; W1 streamed with 4-row prefetch. 4 k-teams,
// LDS tree-reduce, fp32 throughout.
__global__ __launch_bounds__(1024, 4) void k_mlp1(const float* __restrict__ A,
                                                  const float* __restrict__ W1,
                                                  float* __restrict__ part) {
  __shared__ float Asm[32][260];
  __shared__ float4 red[3][4][2][128];
  const int tid = threadIdx.x;
  const int b = blockIdx.x;
  const int k0 = b * 256;
  const int cq = tid & 127;           // 128 col-quads -> 512 cols
  const int team = (tid >> 7) & 3;    // 4 k-teams of 64
  const int mh = tid >> 9;            // 2 m-halves of 16
#pragma unroll
  for (int i = 0; i < 2; ++i) {
    int idx = tid + i * 1024;         // 0..2047 = 32 rows x 64 quads
    int m = idx >> 6;
    int kq = idx & 63;
    float4 v = *reinterpret_cast<const float4*>(&A[(size_t)m * NDG + k0 + kq * 4]);
    *reinterpret_cast<float4*>(&Asm[m][kq * 4]) = v;
  }
  __syncthreads();
  float4 acc[16];
#pragma unroll
  for (int m = 0; m < 16; ++m) acc[m] = make_float4(0.f, 0.f, 0.f, 0.f);
  const int kt0 = team * 64;
  const float* wp = &W1[((size_t)k0 + kt0) * HH + cq * 4];
  float4 wc[4], wn[4];
#pragma unroll
  for (int j = 0; j < 4; ++j)
    wc[j] = *reinterpret_cast<const float4*>(&wp[(size_t)j * HH]);
  for (int it = 0; it < 16; ++it) {
    if (it < 15) {
#pragma unroll
      for (int j = 0; j < 4; ++j)
        wn[j] = *reinterpret_cast<const float4*>(&wp[(size_t)((it + 1) * 4 + j) * HH]);
    }
    const int kk = kt0 + it * 4;
#pragma unroll
    for (int m = 0; m < 16; ++m) {
      float4 a = *reinterpret_cast<const float4*>(&Asm[mh * 16 + m][kk]);
      acc[m].x += a.x * wc[0].x; acc[m].y += a.x * wc[0].y;
      acc[m].z += a.x * wc[0].z; acc[m].w += a.x * wc[0].w;
      acc[m].x += a.y * wc[1].x; acc[m].y += a.y * wc[1].y;
      acc[m].z += a.y * wc[1].z; acc[m].w += a.y * wc[1].w;
      acc[m].x += a.z * wc[2].x; acc[m].y += a.z * wc[2].y;
      acc[m].z += a.z * wc[2].z; acc[m].w += a.z * wc[2].w;
      acc[m].x += a.w * wc[3].x; acc[m].y += a.w * wc[3].y;
      acc[m].z += a.w * wc[3].z; acc[m].w += a.w * wc[3].w;
    }
#pragma unroll
    for (int j = 0; j < 4; ++j) wc[j] = wn[j];
  }
  // reduce 4 teams -> team 0
#pragma unroll
  for (int rg = 0; rg < 4; ++rg) {
    __syncthreads();
    if (team > 0) {
#pragma unroll
      for (int r = 0; r < 4; ++r) red[team - 1][r][mh][cq] = acc[rg * 4 + r];
    }
    __syncthreads();
    if (team == 0) {
#pragma unroll
      for (int r = 0; r < 4; ++r) {
        float4 s = acc[rg * 4 + r];
        float4 p0 = red[0][r][mh][cq];
        float4 p1 = red[1][r][mh][cq];
        float4 p2 = red[2][r][mh][cq];
        s.x += p0.x + p1.x + p2.x; s.y += p0.y + p1.y + p2.y;
        s.z += p0.z + p1.z + p2.z; s.w += p0.w + p1.w + p2.w;
        *reinterpret_cast<float4*>(
            &part[((size_t)b * 32 + mh * 16 + rg * 4 + r) * HH + cq * 4]) = s;
      }
    }
  }
}

// ---------------- K5b: h = relu(sum_b part + b1) ------------------------------
__global__ __launch_bounds__(256) void k_mlp1r(const float* __restrict__ part,
                                               const float* __restrict__ b1,
                                               float* __restrict__ h) {
  __shared__ float red[3][64];
  const int tid = threadIdx.x;
  const int m = blockIdx.x >> 3;
  const int c = (blockIdx.x & 7) * 64 + (tid & 63);
  const int bq = tid >> 6;
  float s = 0.0f;
  for (int bb = bq * 64; bb < bq * 64 + 64; ++bb)
    s += part[((size_t)bb * 32 + m) * 512 + c];
  if (bq > 0) red[bq - 1][tid & 63] = s;
  __syncthreads();
  if (bq == 0) {
    s += red[0][tid & 63] + red[1][tid & 63] + red[2][tid & 63];
    s += b1[c];
    h[m * HH + c] = s > 0.0f ? s : 0.0f;
  }
}

// ---------------- K6: out = h @ W2 + b2 ---------------------------------------
__global__ __launch_bounds__(256) void k_out(const float* __restrict__ h,
                                             const float* __restrict__ W2,
                                             const float* __restrict__ b2,
                                             float* __restrict__ outp) {
  const int tid = threadIdx.x;
  const int m = blockIdx.x * 4 + (tid >> 6);
  const int lane = tid & 63;
  float s = 0.0f;
#pragma unroll
  for (int j = 0; j < 8; ++j) s += h[m * HH + lane + 64 * j] * W2[lane + 64 * j];
#pragma unroll
  for (int off = 1; off < 64; off <<= 1) s += __shfl_xor(s, off);
  if (lane == 0) outp[m] = s + b2[0];
}

extern "C" void kernel_launch(void* const* d_in, const int* in_sizes, int n_in,
                              void* d_out, int out_size, void* d_ws, size_t ws_size,
                              hipStream_t stream) {
  const float* xi     = (const float*)d_in[0];
  const float* W_img  = (const float*)d_in[1];
  const float* b_img  = (const float*)d_in[2];
  const float* W_self = (const float*)d_in[3];
  const float* W_nbr  = (const float*)d_in[4];
  const float* b_gnn  = (const float*)d_in[5];
  const float* W1     = (const float*)d_in[6];
  const float* b1     = (const float*)d_in[7];
  const float* W2     = (const float*)d_in[8];
  const float* b2     = (const float*)d_in[9];
  const int*   kp     = (const int*)d_in[10];

  float* xie  = (float*)d_out;
  float* gep  = xie + (size_t)MM * DD;
  float* outp = gep + (size_t)MM * DD;

  float* ws   = (float*)d_ws;
  float* x2   = ws;                                   // 8192
  int*   nbr  = (int*)(ws + MM);                      // 131072 ints
  float* d2   = ws + MM + MM * KSTR;                  // 8192*256
  float* part = d2 + (size_t)MM * DD;                 // 256*32*512
  float* hbuf = part + (size_t)256 * 32 * HH;         // 32*512
  unsigned short* A_bf  = (unsigned short*)(hbuf + BB * HH);  // 8192*512 bf16
  unsigned short* B_bfT = A_bf + (size_t)MM * 512;            // 256*512 bf16

  k_enc  <<<MM / 32, 256, 0, stream>>>(xi, W_img, b_img, xie, A_bf);
  k_cvtw <<<512, 256, 0, stream>>>(W_self, W_nbr, B_bfT);
  k_norm <<<MM / 4, 256, 0, stream>>>(xie, x2);
  k_dist <<<dim3(4, 4, BB), 256, 0, stream>>>(xie, x2, d2);
  k_topk <<<MM / 4, 256, 0, stream>>>(d2, kp, nbr);
  k_agg  <<<MM, 256, 0, stream>>>(xie, nbr, kp, A_bf);
  k_gnn  <<<dim3(128, 4), 256, 0, stream>>>(A_bf, B_bfT, b_gnn, gep);
  k_mlp1 <<<256, 1024, 0, stream>>>(gep, W1, part);
  k_mlp1r<<<256, 256, 0, stream>>>(part, b1, hbuf);
  k_out  <<<8, 256, 0, stream>>>(hbuf, W2, b2, outp);
}

// Round 4
// 169.584 us; speedup vs baseline: 1.0035x; 1.0035x over previous
//
#include <hip/hip_runtime.h>

#define BB 32
#define NN 256
#define DIN 512
#define DD 256
#define HH 512
#define MM 8192      // BB*NN
#define NDG 65536    // NN*DD
#define KSTR 16

typedef __attribute__((ext_vector_type(8))) __bf16 bf16x8;
typedef __attribute__((ext_vector_type(4))) float f32x4;

__device__ __forceinline__ unsigned short f2bf(float x) {
  unsigned u = __float_as_uint(x);
  u += 0x7FFFu + ((u >> 16) & 1u);   // round-to-nearest-even
  return (unsigned short)(u >> 16);
}

// ---------------- K1: xie = xi @ W_img + b_img  (8192x512 @ 512x256) ----------
// 512 thr / block, 32-row tile. Thread = 4 rows x 8 cols (acc = 32 VGPR).
// cg = tid&31 (8-col group), mh = (tid>>5)&7 (4-row group), team = tid>>8
// (k-half of 256). A tile staged [32][520] in LDS, read as wave-2-address
// b128 broadcasts along k (free). W_img streamed from L2, double-buffered.
// Cross-team reduce through LDS; epilogue writes fp32 xie + bf16 A_bf.
__global__ __launch_bounds__(512) void k_enc(const float* __restrict__ A,
                                             const float* __restrict__ W,
                                             const float* __restrict__ bias,
                                             float* __restrict__ C,
                                             unsigned short* __restrict__ A_bf) {
  __shared__ float Asm[32][520];
  const int tid = threadIdx.x;
  const int mb0 = blockIdx.x * 32;
  const int cg = tid & 31;
  const int mh = (tid >> 5) & 7;
  const int team = tid >> 8;
#pragma unroll
  for (int i = 0; i < 8; ++i) {
    int idx = tid + i * 512;          // 4096 quads = 32 rows x 128
    int m = idx >> 7;
    int kq = idx & 127;
    float4 v = *reinterpret_cast<const float4*>(&A[(size_t)(mb0 + m) * DIN + kq * 4]);
    *reinterpret_cast<float4*>(&Asm[m][kq * 4]) = v;
  }
  __syncthreads();
  float4 acc[4][2] = {};
  const int kt0 = team * 256;
  const float* wp = &W[(size_t)kt0 * DD + cg * 8];
  float4 wA[4][2], wB[4][2];
#pragma unroll
  for (int j = 0; j < 4; ++j) {
    wA[j][0] = *reinterpret_cast<const float4*>(&wp[(size_t)j * DD]);
    wA[j][1] = *reinterpret_cast<const float4*>(&wp[(size_t)j * DD + 4]);
  }
  for (int it = 0; it < 64; ++it) {
    if (it < 63) {
#pragma unroll
      for (int j = 0; j < 4; ++j) {
        wB[j][0] = *reinterpret_cast<const float4*>(&wp[(size_t)((it + 1) * 4 + j) * DD]);
        wB[j][1] = *reinterpret_cast<const float4*>(&wp[(size_t)((it + 1) * 4 + j) * DD + 4]);
      }
    }
    const int kk = kt0 + it * 4;
#pragma unroll
    for (int r = 0; r < 4; ++r) {
      float4 a = *reinterpret_cast<const float4*>(&Asm[mh * 4 + r][kk]);
#pragma unroll
      for (int h = 0; h < 2; ++h) {
        acc[r][h].x += a.x * wA[0][h].x; acc[r][h].y += a.x * wA[0][h].y;
        acc[r][h].z += a.x * wA[0][h].z; acc[r][h].w += a.x * wA[0][h].w;
        acc[r][h].x += a.y * wA[1][h].x; acc[r][h].y += a.y * wA[1][h].y;
        acc[r][h].z += a.y * wA[1][h].z; acc[r][h].w += a.y * wA[1][h].w;
        acc[r][h].x += a.z * wA[2][h].x; acc[r][h].y += a.z * wA[2][h].y;
        acc[r][h].z += a.z * wA[2][h].z; acc[r][h].w += a.z * wA[2][h].w;
        acc[r][h].x += a.w * wA[3][h].x; acc[r][h].y += a.w * wA[3][h].y;
        acc[r][h].z += a.w * wA[3][h].z; acc[r][h].w += a.w * wA[3][h].w;
      }
    }
#pragma unroll
    for (int j = 0; j < 4; ++j) {
      wA[j][0] = wB[j][0]; wA[j][1] = wB[j][1];
    }
  }
  // cross-team reduce (A tile dead): red[row][col], stride 256
  __syncthreads();
  float* red = &Asm[0][0];
  if (team == 1) {
#pragma unroll
    for (int r = 0; r < 4; ++r) {
      *reinterpret_cast<float4*>(&red[(mh * 4 + r) * 256 + cg * 8]) = acc[r][0];
      *reinterpret_cast<float4*>(&red[(mh * 4 + r) * 256 + cg * 8 + 4]) = acc[r][1];
    }
  }
  __syncthreads();
  if (team == 0) {
    float4 bv0 = *reinterpret_cast<const float4*>(&bias[cg * 8]);
    float4 bv1 = *reinterpret_cast<const float4*>(&bias[cg * 8 + 4]);
#pragma unroll
    for (int r = 0; r < 4; ++r) {
      const int row = mb0 + mh * 4 + r;
      float4 o0 = *reinterpret_cast<float4*>(&red[(mh * 4 + r) * 256 + cg * 8]);
      float4 o1 = *reinterpret_cast<float4*>(&red[(mh * 4 + r) * 256 + cg * 8 + 4]);
      float4 s0, s1;
      s0.x = acc[r][0].x + o0.x + bv0.x; s0.y = acc[r][0].y + o0.y + bv0.y;
      s0.z = acc[r][0].z + o0.z + bv0.z; s0.w = acc[r][0].w + o0.w + bv0.w;
      s1.x = acc[r][1].x + o1.x + bv1.x; s1.y = acc[r][1].y + o1.y + bv1.y;
      s1.z = acc[r][1].z + o1.z + bv1.z; s1.w = acc[r][1].w + o1.w + bv1.w;
      *reinterpret_cast<float4*>(&C[(size_t)row * DD + cg * 8]) = s0;
      *reinterpret_cast<float4*>(&C[(size_t)row * DD + cg * 8 + 4]) = s1;
      ushort4 ob0, ob1;
      ob0.x = f2bf(s0.x); ob0.y = f2bf(s0.y); ob0.z = f2bf(s0.z); ob0.w = f2bf(s0.w);
      ob1.x = f2bf(s1.x); ob1.y = f2bf(s1.y); ob1.z = f2bf(s1.z); ob1.w = f2bf(s1.w);
      *reinterpret_cast<ushort4*>(&A_bf[(size_t)row * 512 + cg * 8]) = ob0;
      *reinterpret_cast<ushort4*>(&A_bf[(size_t)row * 512 + cg * 8 + 4]) = ob1;
    }
  }
}

// ---------------- K1b: row norms ----------------------------------------------
__global__ __launch_bounds__(256) void k_norm(const float* __restrict__ X,
                                              float* __restrict__ x2) {
  const int tid = threadIdx.x;
  const int row = blockIdx.x * 4 + (tid >> 6);
  const int lane = tid & 63;
  float4 v = *reinterpret_cast<const float4*>(&X[row * DD + lane * 4]);
  float s = v.x * v.x + v.y * v.y + v.z * v.z + v.w * v.w;
#pragma unroll
  for (int off = 1; off < 64; off <<= 1) s += __shfl_xor(s, off);
  if (lane == 0) x2[row] = s;
}

// ---------------- K2a: pairwise d2 --------------------------------------------
__global__ __launch_bounds__(256) void k_dist(const float* __restrict__ X,
                                              const float* __restrict__ x2,
                                              float* __restrict__ d2) {
  __shared__ float As[16][68];
  __shared__ float Bs[16][68];
  const int tid = threadIdx.x;
  const int b = blockIdx.z;
  const int m0 = blockIdx.x * 64, n0 = blockIdx.y * 64;
  const float* Xb = X + b * NN * DD;
  const int tx = tid & 15, ty = tid >> 4;
  const int lrow = tid >> 2, lfc = (tid & 3) * 4;
  float acc[4][4] = {};
  for (int k0 = 0; k0 < DD; k0 += 16) {
    float4 va = *reinterpret_cast<const float4*>(&Xb[(n0 + lrow) * DD + k0 + lfc]);
    As[lfc + 0][lrow] = va.x; As[lfc + 1][lrow] = va.y;
    As[lfc + 2][lrow] = va.z; As[lfc + 3][lrow] = va.w;
    float4 vb = *reinterpret_cast<const float4*>(&Xb[(m0 + lrow) * DD + k0 + lfc]);
    Bs[lfc + 0][lrow] = vb.x; Bs[lfc + 1][lrow] = vb.y;
    Bs[lfc + 2][lrow] = vb.z; Bs[lfc + 3][lrow] = vb.w;
    __syncthreads();
#pragma unroll
    for (int kk = 0; kk < 16; ++kk) {
      float a[4], bv[4];
      *reinterpret_cast<float4*>(a) = *reinterpret_cast<float4*>(&As[kk][ty * 4]);
      *reinterpret_cast<float4*>(bv) = *reinterpret_cast<float4*>(&Bs[kk][tx * 4]);
#pragma unroll
      for (int i = 0; i < 4; ++i)
#pragma unroll
        for (int j = 0; j < 4; ++j) acc[i][j] += a[i] * bv[j];
    }
    __syncthreads();
  }
#pragma unroll
  for (int i = 0; i < 4; ++i) {
    const int n = n0 + ty * 4 + i;
    const float xn = x2[b * NN + n];
    float4 v;
    float* vv = reinterpret_cast<float*>(&v);
#pragma unroll
    for (int j = 0; j < 4; ++j) {
      const int mc = m0 + tx * 4 + j;
      float dv = xn + x2[b * NN + mc] - 2.0f * acc[i][j];
      if (n == mc) dv = 1e30f;
      vv[j] = dv;
    }
    *reinterpret_cast<float4*>(&d2[(b * NN + n) * NN + m0 + tx * 4]) = v;
  }
}

// ---------------- K2b: per-row top-k ------------------------------------------
__global__ __launch_bounds__(256) void k_topk(const float* __restrict__ d2,
                                              const int* __restrict__ kp,
                                              int* __restrict__ nbr) {
  const int tid = threadIdx.x;
  const int i = blockIdx.x * 4 + (tid >> 6);
  const int lane = tid & 63;
  const int kcnt = kp[0];
  const float* row = d2 + (size_t)i * NN;
  float v0 = row[lane];
  float v1 = row[lane + 64];
  float v2 = row[lane + 128];
  float v3 = row[lane + 192];
  for (int it = 0; it < kcnt; ++it) {
    float v = v0; int idx = lane;
    if (v1 < v) { v = v1; idx = lane + 64; }
    if (v2 < v) { v = v2; idx = lane + 128; }
    if (v3 < v) { v = v3; idx = lane + 192; }
#pragma unroll
    for (int off = 1; off < 64; off <<= 1) {
      float ov = __shfl_xor(v, off);
      int oi = __shfl_xor(idx, off);
      if (ov < v || (ov == v && oi < idx)) { v = ov; idx = oi; }
    }
    if (lane == 0) nbr[i * KSTR + it] = idx;
    const int slot = idx >> 6;
    if (lane == (idx & 63)) {
      if (slot == 0) v0 = 3e38f;
      else if (slot == 1) v1 = 3e38f;
      else if (slot == 2) v2 = 3e38f;
      else v3 = 3e38f;
    }
  }
}

// ---------------- K3: agg (bf16, written into packed A_bf cols 256..511) ------
__global__ __launch_bounds__(256) void k_agg(const float* __restrict__ X,
                                             const int* __restrict__ nbr,
                                             const int* __restrict__ kp,
                                             unsigned short* __restrict__ A_bf) {
  const int i = blockIdx.x;
  const int b = i >> 8;
  const int t = threadIdx.x;
  const int kcnt = kp[0];
  float acc = 0.0f;
  for (int j = 0; j < kcnt; ++j) {
    const int nb = nbr[i * KSTR + j];
    acc += X[(b * NN + nb) * DD + t];
  }
  A_bf[(size_t)i * 512 + 256 + t] = f2bf(acc / (float)kcnt);
}

// ---------------- cvt: [Ws;Wn] -> bf16 transposed B_bfT[n][k] -----------------
__global__ __launch_bounds__(256) void k_cvtw(const float* __restrict__ Ws,
                                              const float* __restrict__ Wn,
                                              unsigned short* __restrict__ B_bfT) {
  const int id = blockIdx.x * 256 + threadIdx.x;    // 0 .. 131071
  const int k = id >> 8;
  const int n = id & 255;
  float v = (k < 256) ? Ws[k * 256 + n] : Wn[(k - 256) * 256 + n];
  B_bfT[(size_t)n * 512 + k] = f2bf(v);
}

// ---------------- K4: gep = relu(A_bf @ B_bfT^T + b) via bf16 MFMA ------------
__global__ __launch_bounds__(256) void k_gnn(const unsigned short* __restrict__ A_bf,
                                             const unsigned short* __restrict__ B_bfT,
                                             const float* __restrict__ bias,
                                             float* __restrict__ C) {
  __shared__ unsigned short As[64 * 72];
  __shared__ unsigned short Bs[64 * 72];
  const int tid = threadIdx.x;
  const int m0 = blockIdx.x * 64, n0 = blockIdx.y * 64;
  const int l = tid & 63, w = tid >> 6;
  const int mw = (w & 1) * 32, nw = (w >> 1) * 32;
  const int lr = tid >> 3, lq = tid & 7;
  f32x4 acc[2][2] = {};
  for (int kt = 0; kt < 8; ++kt) {
    const int kb = kt * 64;
#pragma unroll
    for (int s = 0; s < 2; ++s) {
      const int r = lr + s * 32;
      uint4 va = *reinterpret_cast<const uint4*>(&A_bf[(size_t)(m0 + r) * 512 + kb + lq * 8]);
      *reinterpret_cast<uint4*>(&As[r * 72 + lq * 8]) = va;
      uint4 vb = *reinterpret_cast<const uint4*>(&B_bfT[(size_t)(n0 + r) * 512 + kb + lq * 8]);
      *reinterpret_cast<uint4*>(&Bs[r * 72 + lq * 8]) = vb;
    }
    __syncthreads();
#pragma unroll
    for (int ks = 0; ks < 2; ++ks) {
      bf16x8 af[2], bf[2];
#pragma unroll
      for (int mi = 0; mi < 2; ++mi)
        af[mi] = *reinterpret_cast<const bf16x8*>(
            &As[(mw + mi * 16 + (l & 15)) * 72 + ks * 32 + (l >> 4) * 8]);
#pragma unroll
      for (int ni = 0; ni < 2; ++ni)
        bf[ni] = *reinterpret_cast<const bf16x8*>(
            &Bs[(nw + ni * 16 + (l & 15)) * 72 + ks * 32 + (l >> 4) * 8]);
#pragma unroll
      for (int mi = 0; mi < 2; ++mi)
#pragma unroll
        for (int ni = 0; ni < 2; ++ni)
          acc[mi][ni] = __builtin_amdgcn_mfma_f32_16x16x32_bf16(af[mi], bf[ni],
                                                                acc[mi][ni], 0, 0, 0);
    }
    __syncthreads();
  }
#pragma unroll
  for (int mi = 0; mi < 2; ++mi) {
    const int row_base = m0 + mw + mi * 16 + (l >> 4) * 4;
#pragma unroll
    for (int ni = 0; ni < 2; ++ni) {
      const int col = n0 + nw + ni * 16 + (l & 15);
      const float bv = bias[col];
#pragma unroll
      for (int r = 0; r < 4; ++r) {
        float v = acc[mi][ni][r] + bv;
        C[(size_t)(row_base + r) * 256 + col] = v > 0.0f ? v : 0.0f;
      }
    }
  }
}

// ---------------- K5: h partials = gep_flat[32,65536] @ W1, k-chunked ---------
// 256 blocks x 512 thr. Block b owns k in [b*256, b*256+256).
// Thread = 8 rows x 4 cols (acc = 32 VGPR). cq = tid&127 (col-quad),
// mh = tid>>7 (8-row group, wave-uniform). A tile [32][260] in LDS, read as
// wave-uniform b128 broadcasts along k. W1 streamed once from HBM with 8-row
// (2-step) double-buffered prefetch (64 VGPR). Total ~120 VGPR, no cap.
__global__ __launch_bounds__(512) void k_mlp1(const float* __restrict__ A,
                                              const float* __restrict__ W1,
                                              float* __restrict__ part) {
  __shared__ float Asm[32][260];
  const int tid = threadIdx.x;
  const int b = blockIdx.x;
  const int k0 = b * 256;
  const int cq = tid & 127;
  const int mh = tid >> 7;
#pragma unroll
  for (int i = 0; i < 4; ++i) {
    int idx = tid + i * 512;          // 2048 quads = 32 rows x 64
    int m = idx >> 6;
    int kq = idx & 63;
    float4 v = *reinterpret_cast<const float4*>(&A[(size_t)m * NDG + k0 + kq * 4]);
    *reinterpret_cast<float4*>(&Asm[m][kq * 4]) = v;
  }
  __syncthreads();
  float4 acc[8] = {};
  const float* wp = &W1[(size_t)k0 * HH + cq * 4];
  float4 wA[8], wB[8];
#pragma unroll
  for (int j = 0; j < 8; ++j)
    wA[j] = *reinterpret_cast<const float4*>(&wp[(size_t)j * HH]);
  for (int it = 0; it < 32; ++it) {   // 8 k per iteration
    if (it < 31) {
#pragma unroll
      for (int j = 0; j < 8; ++j)
        wB[j] = *reinterpret_cast<const float4*>(&wp[(size_t)((it + 1) * 8 + j) * HH]);
    }
#pragma unroll
    for (int half = 0; half < 2; ++half) {
      const int kk = it * 8 + half * 4;
#pragma unroll
      for (int r = 0; r < 8; ++r) {
        float4 a = *reinterpret_cast<const float4*>(&Asm[mh * 8 + r][kk]);
        acc[r].x += a.x * wA[half * 4 + 0].x; acc[r].y += a.x * wA[half * 4 + 0].y;
        acc[r].z += a.x * wA[half * 4 + 0].z; acc[r].w += a.x * wA[half * 4 + 0].w;
        acc[r].x += a.y * wA[half * 4 + 1].x; acc[r].y += a.y * wA[half * 4 + 1].y;
        acc[r].z += a.y * wA[half * 4 + 1].z; acc[r].w += a.y * wA[half * 4 + 1].w;
        acc[r].x += a.z * wA[half * 4 + 2].x; acc[r].y += a.z * wA[half * 4 + 2].y;
        acc[r].z += a.z * wA[half * 4 + 2].z; acc[r].w += a.z * wA[half * 4 + 2].w;
        acc[r].x += a.w * wA[half * 4 + 3].x; acc[r].y += a.w * wA[half * 4 + 3].y;
        acc[r].z += a.w * wA[half * 4 + 3].z; acc[r].w += a.w * wA[half * 4 + 3].w;
      }
    }
#pragma unroll
    for (int j = 0; j < 8; ++j) wA[j] = wB[j];
  }
#pragma unroll
  for (int r = 0; r < 8; ++r)
    *reinterpret_cast<float4*>(
        &part[((size_t)b * 32 + mh * 8 + r) * HH + cq * 4]) = acc[r];
}

// ---------------- K5b: h = relu(sum_b part + b1) ------------------------------
__global__ __launch_bounds__(256) void k_mlp1r(const float* __restrict__ part,
                                               const float* __restrict__ b1,
                                               float* __restrict__ h) {
  __shared__ float red[3][64];
  const int tid = threadIdx.x;
  const int m = blockIdx.x >> 3;
  const int c = (blockIdx.x & 7) * 64 + (tid & 63);
  const int bq = tid >> 6;
  float s = 0.0f;
  for (int bb = bq * 64; bb < bq * 64 + 64; ++bb)
    s += part[((size_t)bb * 32 + m) * 512 + c];
  if (bq > 0) red[bq - 1][tid & 63] = s;
  __syncthreads();
  if (bq == 0) {
    s += red[0][tid & 63] + red[1][tid & 63] + red[2][tid & 63];
    s += b1[c];
    h[m * HH + c] = s > 0.0f ? s : 0.0f;
  }
}

// ---------------- K6: out = h @ W2 + b2 ---------------------------------------
__global__ __launch_bounds__(256) void k_out(const float* __restrict__ h,
                                             const float* __restrict__ W2,
                                             const float* __restrict__ b2,
                                             float* __restrict__ outp) {
  const int tid = threadIdx.x;
  const int m = blockIdx.x * 4 + (tid >> 6);
  const int lane = tid & 63;
  float s = 0.0f;
#pragma unroll
  for (int j = 0; j < 8; ++j) s += h[m * HH + lane + 64 * j] * W2[lane + 64 * j];
#pragma unroll
  for (int off = 1; off < 64; off <<= 1) s += __shfl_xor(s, off);
  if (lane == 0) outp[m] = s + b2[0];
}

extern "C" void kernel_launch(void* const* d_in, const int* in_sizes, int n_in,
                              void* d_out, int out_size, void* d_ws, size_t ws_size,
                              hipStream_t stream) {
  const float* xi     = (const float*)d_in[0];
  const float* W_img  = (const float*)d_in[1];
  const float* b_img  = (const float*)d_in[2];
  const float* W_self = (const float*)d_in[3];
  const float* W_nbr  = (const float*)d_in[4];
  const float* b_gnn  = (const float*)d_in[5];
  const float* W1     = (const float*)d_in[6];
  const float* b1     = (const float*)d_in[7];
  const float* W2     = (const float*)d_in[8];
  const float* b2     = (const float*)d_in[9];
  const int*   kp     = (const int*)d_in[10];

  float* xie  = (float*)d_out;
  float* gep  = xie + (size_t)MM * DD;
  float* outp = gep + (size_t)MM * DD;

  float* ws   = (float*)d_ws;
  float* x2   = ws;                                   // 8192
  int*   nbr  = (int*)(ws + MM);                      // 131072 ints
  float* d2   = ws + MM + MM * KSTR;                  // 8192*256
  float* part = d2 + (size_t)MM * DD;                 // 256*32*512
  float* hbuf = part + (size_t)256 * 32 * HH;         // 32*512
  unsigned short* A_bf  = (unsigned short*)(hbuf + BB * HH);  // 8192*512 bf16
  unsigned short* B_bfT = A_bf + (size_t)MM * 512;            // 256*512 bf16

  k_enc  <<<MM / 32, 512, 0, stream>>>(xi, W_img, b_img, xie, A_bf);
  k_cvtw <<<512, 256, 0, stream>>>(W_self, W_nbr, B_bfT);
  k_norm <<<MM / 4, 256, 0, stream>>>(xie, x2);
  k_dist <<<dim3(4, 4, BB), 256, 0, stream>>>(xie, x2, d2);
  k_topk <<<MM / 4, 256, 0, stream>>>(d2, kp, nbr);
  k_agg  <<<MM, 256, 0, stream>>>(xie, nbr, kp, A_bf);
  k_gnn  <<<dim3(128, 4), 256, 0, stream>>>(A_bf, B_bfT, b_gnn, gep);
  k_mlp1 <<<256, 512, 0, stream>>>(gep, W1, part);
  k_mlp1r<<<256, 256, 0, stream>>>(part, b1, hbuf);
  k_out  <<<8, 256, 0, stream>>>(hbuf, W2, b2, outp);
}

// Round 6
// 160.034 us; speedup vs baseline: 1.0634x; 1.0597x over previous
//
#include <hip/hip_runtime.h>

#define BB 32
#define NN 256
#define DIN 512
#define DD 256
#define HH 512
#define MM 8192      // BB*NN
#define NDG 65536    // NN*DD
#define KSTR 16

typedef __attribute__((ext_vector_type(8))) __bf16 bf16x8;
typedef __attribute__((ext_vector_type(4))) float f32x4;
typedef unsigned short ushort_t;

__device__ __forceinline__ unsigned short f2bf(float x) {
  unsigned u = __float_as_uint(x);
  u += 0x7FFFu + ((u >> 16) & 1u);   // round-to-nearest-even
  return (unsigned short)(u >> 16);
}

// ---------------- K1: xie = xi @ W_img + b_img (fp32 exact, feeds KNN) --------
// 512 thr / block, 32-row tile. Thread = 4 rows x 8 cols. A tile in LDS,
// wave-uniform b128 broadcast reads along k; W_img streamed (L2-resident).
__global__ __launch_bounds__(512) void k_enc(const float* __restrict__ A,
                                             const float* __restrict__ W,
                                             const float* __restrict__ bias,
                                             float* __restrict__ C,
                                             ushort_t* __restrict__ A_bf) {
  __shared__ float Asm[32][520];
  const int tid = threadIdx.x;
  const int mb0 = blockIdx.x * 32;
  const int cg = tid & 31;
  const int mh = (tid >> 5) & 7;
  const int team = tid >> 8;
#pragma unroll
  for (int i = 0; i < 8; ++i) {
    int idx = tid + i * 512;          // 4096 quads = 32 rows x 128
    int m = idx >> 7;
    int kq = idx & 127;
    float4 v = *reinterpret_cast<const float4*>(&A[(size_t)(mb0 + m) * DIN + kq * 4]);
    *reinterpret_cast<float4*>(&Asm[m][kq * 4]) = v;
  }
  __syncthreads();
  float4 acc[4][2] = {};
  const int kt0 = team * 256;
  const float* wp = &W[(size_t)kt0 * DD + cg * 8];
  float4 wA[4][2], wB[4][2];
#pragma unroll
  for (int j = 0; j < 4; ++j) {
    wA[j][0] = *reinterpret_cast<const float4*>(&wp[(size_t)j * DD]);
    wA[j][1] = *reinterpret_cast<const float4*>(&wp[(size_t)j * DD + 4]);
  }
  for (int it = 0; it < 64; ++it) {
    if (it < 63) {
#pragma unroll
      for (int j = 0; j < 4; ++j) {
        wB[j][0] = *reinterpret_cast<const float4*>(&wp[(size_t)((it + 1) * 4 + j) * DD]);
        wB[j][1] = *reinterpret_cast<const float4*>(&wp[(size_t)((it + 1) * 4 + j) * DD + 4]);
      }
    }
    const int kk = kt0 + it * 4;
#pragma unroll
    for (int r = 0; r < 4; ++r) {
      float4 a = *reinterpret_cast<const float4*>(&Asm[mh * 4 + r][kk]);
#pragma unroll
      for (int h = 0; h < 2; ++h) {
        acc[r][h].x += a.x * wA[0][h].x; acc[r][h].y += a.x * wA[0][h].y;
        acc[r][h].z += a.x * wA[0][h].z; acc[r][h].w += a.x * wA[0][h].w;
        acc[r][h].x += a.y * wA[1][h].x; acc[r][h].y += a.y * wA[1][h].y;
        acc[r][h].z += a.y * wA[1][h].z; acc[r][h].w += a.y * wA[1][h].w;
        acc[r][h].x += a.z * wA[2][h].x; acc[r][h].y += a.z * wA[2][h].y;
        acc[r][h].z += a.z * wA[2][h].z; acc[r][h].w += a.z * wA[2][h].w;
        acc[r][h].x += a.w * wA[3][h].x; acc[r][h].y += a.w * wA[3][h].y;
        acc[r][h].z += a.w * wA[3][h].z; acc[r][h].w += a.w * wA[3][h].w;
      }
    }
#pragma unroll
    for (int j = 0; j < 4; ++j) {
      wA[j][0] = wB[j][0]; wA[j][1] = wB[j][1];
    }
  }
  __syncthreads();
  float* red = &Asm[0][0];
  if (team == 1) {
#pragma unroll
    for (int r = 0; r < 4; ++r) {
      *reinterpret_cast<float4*>(&red[(mh * 4 + r) * 256 + cg * 8]) = acc[r][0];
      *reinterpret_cast<float4*>(&red[(mh * 4 + r) * 256 + cg * 8 + 4]) = acc[r][1];
    }
  }
  __syncthreads();
  if (team == 0) {
    float4 bv0 = *reinterpret_cast<const float4*>(&bias[cg * 8]);
    float4 bv1 = *reinterpret_cast<const float4*>(&bias[cg * 8 + 4]);
#pragma unroll
    for (int r = 0; r < 4; ++r) {
      const int row = mb0 + mh * 4 + r;
      float4 o0 = *reinterpret_cast<float4*>(&red[(mh * 4 + r) * 256 + cg * 8]);
      float4 o1 = *reinterpret_cast<float4*>(&red[(mh * 4 + r) * 256 + cg * 8 + 4]);
      float4 s0, s1;
      s0.x = acc[r][0].x + o0.x + bv0.x; s0.y = acc[r][0].y + o0.y + bv0.y;
      s0.z = acc[r][0].z + o0.z + bv0.z; s0.w = acc[r][0].w + o0.w + bv0.w;
      s1.x = acc[r][1].x + o1.x + bv1.x; s1.y = acc[r][1].y + o1.y + bv1.y;
      s1.z = acc[r][1].z + o1.z + bv1.z; s1.w = acc[r][1].w + o1.w + bv1.w;
      *reinterpret_cast<float4*>(&C[(size_t)row * DD + cg * 8]) = s0;
      *reinterpret_cast<float4*>(&C[(size_t)row * DD + cg * 8 + 4]) = s1;
      ushort4 ob0, ob1;
      ob0.x = f2bf(s0.x); ob0.y = f2bf(s0.y); ob0.z = f2bf(s0.z); ob0.w = f2bf(s0.w);
      ob1.x = f2bf(s1.x); ob1.y = f2bf(s1.y); ob1.z = f2bf(s1.z); ob1.w = f2bf(s1.w);
      *reinterpret_cast<ushort4*>(&A_bf[(size_t)row * 512 + cg * 8]) = ob0;
      *reinterpret_cast<ushort4*>(&A_bf[(size_t)row * 512 + cg * 8 + 4]) = ob1;
    }
  }
}

// ---------------- K1b: row norms ----------------------------------------------
__global__ __launch_bounds__(256) void k_norm(const float* __restrict__ X,
                                              float* __restrict__ x2) {
  const int tid = threadIdx.x;
  const int row = blockIdx.x * 4 + (tid >> 6);
  const int lane = tid & 63;
  float4 v = *reinterpret_cast<const float4*>(&X[(size_t)row * DD + lane * 4]);
  float s = v.x * v.x + v.y * v.y + v.z * v.z + v.w * v.w;
#pragma unroll
  for (int off = 1; off < 64; off <<= 1) s += __shfl_xor(s, off);
  if (lane == 0) x2[row] = s;
}

// ---------------- K2a: pairwise d2 (fp32 exact, feeds top-k) ------------------
__global__ __launch_bounds__(256) void k_dist(const float* __restrict__ X,
                                              const float* __restrict__ x2,
                                              float* __restrict__ d2) {
  __shared__ float As[16][68];
  __shared__ float Bs[16][68];
  const int tid = threadIdx.x;
  const int b = blockIdx.z;
  const int m0 = blockIdx.x * 64, n0 = blockIdx.y * 64;
  const float* Xb = X + b * NN * DD;
  const int tx = tid & 15, ty = tid >> 4;
  const int lrow = tid >> 2, lfc = (tid & 3) * 4;
  float acc[4][4] = {};
  for (int k0 = 0; k0 < DD; k0 += 16) {
    float4 va = *reinterpret_cast<const float4*>(&Xb[(n0 + lrow) * DD + k0 + lfc]);
    As[lfc + 0][lrow] = va.x; As[lfc + 1][lrow] = va.y;
    As[lfc + 2][lrow] = va.z; As[lfc + 3][lrow] = va.w;
    float4 vb = *reinterpret_cast<const float4*>(&Xb[(m0 + lrow) * DD + k0 + lfc]);
    Bs[lfc + 0][lrow] = vb.x; Bs[lfc + 1][lrow] = vb.y;
    Bs[lfc + 2][lrow] = vb.z; Bs[lfc + 3][lrow] = vb.w;
    __syncthreads();
#pragma unroll
    for (int kk = 0; kk < 16; ++kk) {
      float a[4], bv[4];
      *reinterpret_cast<float4*>(a) = *reinterpret_cast<float4*>(&As[kk][ty * 4]);
      *reinterpret_cast<float4*>(bv) = *reinterpret_cast<float4*>(&Bs[kk][tx * 4]);
#pragma unroll
      for (int i = 0; i < 4; ++i)
#pragma unroll
        for (int j = 0; j < 4; ++j) acc[i][j] += a[i] * bv[j];
    }
    __syncthreads();
  }
#pragma unroll
  for (int i = 0; i < 4; ++i) {
    const int n = n0 + ty * 4 + i;
    const float xn = x2[b * NN + n];
    float4 v;
    float* vv = reinterpret_cast<float*>(&v);
#pragma unroll
    for (int j = 0; j < 4; ++j) {
      const int mc = m0 + tx * 4 + j;
      float dv = xn + x2[b * NN + mc] - 2.0f * acc[i][j];
      if (n == mc) dv = 1e30f;
      vv[j] = dv;
    }
    *reinterpret_cast<float4*>(&d2[(size_t)(b * NN + n) * NN + m0 + tx * 4]) = v;
  }
}

// ---------------- K2b: per-row top-k ------------------------------------------
__global__ __launch_bounds__(256) void k_topk(const float* __restrict__ d2,
                                              const int* __restrict__ kp,
                                              int* __restrict__ nbr) {
  const int tid = threadIdx.x;
  const int i = blockIdx.x * 4 + (tid >> 6);
  const int lane = tid & 63;
  const int kcnt = kp[0];
  const float* row = d2 + (size_t)i * NN;
  float v0 = row[lane];
  float v1 = row[lane + 64];
  float v2 = row[lane + 128];
  float v3 = row[lane + 192];
  for (int it = 0; it < kcnt; ++it) {
    float v = v0; int idx = lane;
    if (v1 < v) { v = v1; idx = lane + 64; }
    if (v2 < v) { v = v2; idx = lane + 128; }
    if (v3 < v) { v = v3; idx = lane + 192; }
#pragma unroll
    for (int off = 1; off < 64; off <<= 1) {
      float ov = __shfl_xor(v, off);
      int oi = __shfl_xor(idx, off);
      if (ov < v || (ov == v && oi < idx)) { v = ov; idx = oi; }
    }
    if (lane == 0) nbr[i * KSTR + it] = idx;
    const int slot = idx >> 6;
    if (lane == (idx & 63)) {
      if (slot == 0) v0 = 3e38f;
      else if (slot == 1) v1 = 3e38f;
      else if (slot == 2) v2 = 3e38f;
      else v3 = 3e38f;
    }
  }
}

// ---------------- K3: agg -> A_bf cols 256..511 -------------------------------
__global__ __launch_bounds__(256) void k_agg(const float* __restrict__ X,
                                             const int* __restrict__ nbr,
                                             const int* __restrict__ kp,
                                             ushort_t* __restrict__ A_bf) {
  const int i = blockIdx.x;
  const int b = i >> 8;
  const int t = threadIdx.x;
  const int kcnt = kp[0];
  float acc = 0.0f;
  for (int j = 0; j < kcnt; ++j) {
    const int nb = nbr[i * KSTR + j];
    acc += X[(size_t)(b * NN + nb) * DD + t];
  }
  A_bf[(size_t)i * 512 + 256 + t] = f2bf(acc / (float)kcnt);
}

// ---------------- cvt: [Ws;Wn] -> bf16 transposed B_bfT[n][k] -----------------
__global__ __launch_bounds__(256) void k_cvtw(const float* __restrict__ Ws,
                                              const float* __restrict__ Wn,
                                              ushort_t* __restrict__ B_bfT) {
  const int id = blockIdx.x * 256 + threadIdx.x;    // 0 .. 131071
  const int k = id >> 8;
  const int n = id & 255;
  float v = (k < 256) ? Ws[(size_t)k * 256 + n] : Wn[(size_t)(k - 256) * 256 + n];
  B_bfT[(size_t)n * 512 + k] = f2bf(v);
}

// ---------------- K4: gep = relu(A_bf @ B_bfT^T + b); also gep_bf -------------
__global__ __launch_bounds__(256) void k_gnn(const ushort_t* __restrict__ A_bf,
                                             const ushort_t* __restrict__ B_bfT,
                                             const float* __restrict__ bias,
                                             float* __restrict__ C,
                                             ushort_t* __restrict__ gep_bf) {
  __shared__ ushort_t As[64 * 72];
  __shared__ ushort_t Bs[64 * 72];
  const int tid = threadIdx.x;
  const int m0 = blockIdx.x * 64, n0 = blockIdx.y * 64;
  const int l = tid & 63, w = tid >> 6;
  const int mw = (w & 1) * 32, nw = (w >> 1) * 32;
  const int lr = tid >> 3, lq = tid & 7;
  f32x4 acc[2][2] = {};
  for (int kt = 0; kt < 8; ++kt) {
    const int kb = kt * 64;
#pragma unroll
    for (int s = 0; s < 2; ++s) {
      const int r = lr + s * 32;
      uint4 va = *reinterpret_cast<const uint4*>(&A_bf[(size_t)(m0 + r) * 512 + kb + lq * 8]);
      *reinterpret_cast<uint4*>(&As[r * 72 + lq * 8]) = va;
      uint4 vb = *reinterpret_cast<const uint4*>(&B_bfT[(size_t)(n0 + r) * 512 + kb + lq * 8]);
      *reinterpret_cast<uint4*>(&Bs[r * 72 + lq * 8]) = vb;
    }
    __syncthreads();
#pragma unroll
    for (int ks = 0; ks < 2; ++ks) {
      bf16x8 af[2], bf[2];
#pragma unroll
      for (int mi = 0; mi < 2; ++mi)
        af[mi] = *reinterpret_cast<const bf16x8*>(
            &As[(mw + mi * 16 + (l & 15)) * 72 + ks * 32 + (l >> 4) * 8]);
#pragma unroll
      for (int ni = 0; ni < 2; ++ni)
        bf[ni] = *reinterpret_cast<const bf16x8*>(
            &Bs[(nw + ni * 16 + (l & 15)) * 72 + ks * 32 + (l >> 4) * 8]);
#pragma unroll
      for (int mi = 0; mi < 2; ++mi)
#pragma unroll
        for (int ni = 0; ni < 2; ++ni)
          acc[mi][ni] = __builtin_amdgcn_mfma_f32_16x16x32_bf16(af[mi], bf[ni],
                                                                acc[mi][ni], 0, 0, 0);
    }
    __syncthreads();
  }
#pragma unroll
  for (int mi = 0; mi < 2; ++mi) {
    const int row_base = m0 + mw + mi * 16 + (l >> 4) * 4;
#pragma unroll
    for (int ni = 0; ni < 2; ++ni) {
      const int col = n0 + nw + ni * 16 + (l & 15);
      const float bv = bias[col];
#pragma unroll
      for (int r = 0; r < 4; ++r) {
        float v = acc[mi][ni][r] + bv;
        v = v > 0.0f ? v : 0.0f;
        C[(size_t)(row_base + r) * 256 + col] = v;
        gep_bf[(size_t)(row_base + r) * 256 + col] = f2bf(v);
      }
    }
  }
}

// ------- K5: h partials = gep_bf[32,65536] @ W1 via MFMA ----------------------
// 256 blocks x 256 thr (4 waves), 1 block/CU. Block b = node b's 256-k chunk.
// W1 fp32 staged 32 rows/stage via global_load_lds (16B) double-buffer
// (128 KB LDS), converted to bf16 in-register for B-frags. A = gep_bf 32x256.
typedef const float __attribute__((address_space(1)))* gas1f;
typedef unsigned int __attribute__((address_space(3)))* las3u;

__global__ __launch_bounds__(256) void k_mlp1(const ushort_t* __restrict__ gep_bf,
                                              const float* __restrict__ W1,
                                              float* __restrict__ part) {
  __shared__ float Wb[2][32 * 512];          // 2 x 64 KB
  __shared__ ushort_t Ab[32][264];           // 32 rows x 256 k (pad 8)
  const int tid = threadIdx.x;
  const int b = blockIdx.x;
  const int l = tid & 63, w = tid >> 6;
#pragma unroll
  for (int i = 0; i < 4; ++i) {              // stage A
    int id = tid + i * 256;
    int m = id >> 5, dq8 = (id & 31) * 8;
    *reinterpret_cast<uint4*>(&Ab[m][dq8]) = *reinterpret_cast<const uint4*>(
        &gep_bf[((size_t)m * 256 + b) * 256 + dq8]);
  }
  const float* Wbase = W1 + (size_t)b * 256 * 512;
  auto stage = [&](int kt, int buf) {
    const float* gsrc = Wbase + (size_t)kt * 32 * 512;
#pragma unroll
    for (int i = 0; i < 16; ++i) {
      const int idx = w * 16 + i;            // 64 chunks of 256 floats
      const float* gp = gsrc + idx * 256 + l * 4;
      __builtin_amdgcn_global_load_lds((gas1f)gp, (las3u)&Wb[buf][idx * 256], 16, 0, 0);
    }
  };
  stage(0, 0);
  __syncthreads();
  const int n0w = w * 128;
  f32x4 acc[2][8] = {};
  for (int kt = 0; kt < 8; ++kt) {
    const int cur = kt & 1;
    if (kt < 7) stage(kt + 1, cur ^ 1);
    bf16x8 a[2];
#pragma unroll
    for (int mi = 0; mi < 2; ++mi)
      a[mi] = *reinterpret_cast<const bf16x8*>(&Ab[mi * 16 + (l & 15)][kt * 32 + (l >> 4) * 8]);
    const float* wl = &Wb[cur][0];
    const int kr = (l >> 4) * 8;
#pragma unroll
    for (int nf = 0; nf < 8; ++nf) {
      const int col = n0w + nf * 16 + (l & 15);
      union { unsigned short us[8]; bf16x8 v; } bb;
#pragma unroll
      for (int j = 0; j < 8; ++j)
        bb.us[j] = f2bf(wl[(kr + j) * 512 + col]);
      acc[0][nf] = __builtin_amdgcn_mfma_f32_16x16x32_bf16(a[0], bb.v, acc[0][nf], 0, 0, 0);
      acc[1][nf] = __builtin_amdgcn_mfma_f32_16x16x32_bf16(a[1], bb.v, acc[1][nf], 0, 0, 0);
    }
    __syncthreads();
  }
#pragma unroll
  for (int mi = 0; mi < 2; ++mi)
#pragma unroll
    for (int nf = 0; nf < 8; ++nf) {
      const int col = n0w + nf * 16 + (l & 15);
#pragma unroll
      for (int r = 0; r < 4; ++r) {
        const int m = mi * 16 + (l >> 4) * 4 + r;
        part[((size_t)b * 32 + m) * HH + col] = acc[mi][nf][r];
      }
    }
}

// ---------------- K5b: h = relu(sum_b part + b1) ------------------------------
__global__ __launch_bounds__(256) void k_mlp1r(const float* __restrict__ part,
                                               const float* __restrict__ b1,
                                               float* __restrict__ h) {
  __shared__ float red[3][64];
  const int tid = threadIdx.x;
  const int m = blockIdx.x >> 3;
  const int c = (blockIdx.x & 7) * 64 + (tid & 63);
  const int bq = tid >> 6;
  float s = 0.0f;
  for (int bb = bq * 64; bb < bq * 64 + 64; ++bb)
    s += part[((size_t)bb * 32 + m) * 512 + c];
  if (bq > 0) red[bq - 1][tid & 63] = s;
  __syncthreads();
  if (bq == 0) {
    s += red[0][tid & 63] + red[1][tid & 63] + red[2][tid & 63];
    s += b1[c];
    h[m * HH + c] = s > 0.0f ? s : 0.0f;
  }
}

// ---------------- K6: out = h @ W2 + b2 ---------------------------------------
__global__ __launch_bounds__(256) void k_out(const float* __restrict__ h,
                                             const float* __restrict__ W2,
                                             const float* __restrict__ b2,
                                             float* __restrict__ outp) {
  const int tid = threadIdx.x;
  const int m = blockIdx.x * 4 + (tid >> 6);
  const int lane = tid & 63;
  float s = 0.0f;
#pragma unroll
  for (int j = 0; j < 8; ++j) s += h[m * HH + lane + 64 * j] * W2[lane + 64 * j];
#pragma unroll
  for (int off = 1; off < 64; off <<= 1) s += __shfl_xor(s, off);
  if (lane == 0) outp[m] = s + b2[0];
}

extern "C" void kernel_launch(void* const* d_in, const int* in_sizes, int n_in,
                              void* d_out, int out_size, void* d_ws, size_t ws_size,
                              hipStream_t stream) {
  const float* xi     = (const float*)d_in[0];
  const float* W_img  = (const float*)d_in[1];
  const float* b_img  = (const float*)d_in[2];
  const float* W_self = (const float*)d_in[3];
  const float* W_nbr  = (const float*)d_in[4];
  const float* b_gnn  = (const float*)d_in[5];
  const float* W1     = (const float*)d_in[6];
  const float* b1     = (const float*)d_in[7];
  const float* W2     = (const float*)d_in[8];
  const float* b2     = (const float*)d_in[9];
  const int*   kp     = (const int*)d_in[10];

  float* xie  = (float*)d_out;
  float* gep  = xie + (size_t)MM * DD;
  float* outp = gep + (size_t)MM * DD;

  float* ws   = (float*)d_ws;
  float* x2   = ws;                                   // 8192 f
  int*   nbr  = (int*)(ws + 8192);                    // 131072 i
  float* d2   = ws + 8192 + 131072;                   // 2,097,152 f
  float* part = d2 + (size_t)2097152;                 // 4,194,304 f
  float* hbuf = part + (size_t)4194304;               // 16,384 f
  ushort_t* A_bf   = (ushort_t*)(hbuf + 16384);       // 8192*512 us
  ushort_t* B_bfT  = A_bf + (size_t)MM * 512;         // 131,072 us
  ushort_t* gep_bf = B_bfT + 131072;                  // 2,097,152 us

  k_enc  <<<MM / 32, 512, 0, stream>>>(xi, W_img, b_img, xie, A_bf);
  k_cvtw <<<512, 256, 0, stream>>>(W_self, W_nbr, B_bfT);
  k_norm <<<MM / 4, 256, 0, stream>>>(xie, x2);
  k_dist <<<dim3(4, 4, BB), 256, 0, stream>>>(xie, x2, d2);
  k_topk <<<MM / 4, 256, 0, stream>>>(d2, kp, nbr);
  k_agg  <<<MM, 256, 0, stream>>>(xie, nbr, kp, A_bf);
  k_gnn  <<<dim3(128, 4), 256, 0, stream>>>(A_bf, B_bfT, b_gnn, gep, gep_bf);
  k_mlp1 <<<256, 256, 0, stream>>>(gep_bf, W1, part);
  k_mlp1r<<<256, 256, 0, stream>>>(part, b1, hbuf);
  k_out  <<<8, 256, 0, stream>>>(hbuf, W2, b2, outp);
}